// Round 4
// baseline (220.427 us; speedup 1.0000x reference)
//
#include <hip/hip_runtime.h>
#include <math.h>

// ---- static config (mirrors reference) ----
#define BB 16
#define AA 3
#define NCC 80
#define WW 76
#define MM 32
#define CELLS_PER_IMG (AA * WW * WW)          // 17328
#define NDECODE (BB * CELLS_PER_IMG * 85)     // 23,566,080
#define NCELLS (BB * CELLS_PER_IMG)           // 277,248

typedef float vfloat4 __attribute__((ext_vector_type(4)));

__constant__ float c_anchor[9][2] = {
    {10.f,13.f},{16.f,30.f},{33.f,23.f},{30.f,61.f},{62.f,45.f},
    {59.f,119.f},{116.f,90.f},{156.f,198.f},{373.f,326.f}};

#define LOG2E 1.4426950408889634f

__device__ __forceinline__ float fast_sigmoid(float x) {
    return __builtin_amdgcn_rcpf(1.0f + __builtin_amdgcn_exp2f(-x * LOG2E));
}

// ---------------------------------------------------------------------------
// Kernel 1: branchless streaming sigmoid over the whole tensor. The 4 box
// channels per cell (4/85 of elements) get a WRONG value here; kernel 2
// overwrites them. Nontemporal stores: output is write-once streaming.
// ---------------------------------------------------------------------------
__global__ void bulk_sigmoid_kernel(const vfloat4* __restrict__ in, vfloat4* __restrict__ out) {
    const int n4 = NDECODE / 4;
    int tid = blockIdx.x * blockDim.x + threadIdx.x;
    if (tid >= n4) return;
    vfloat4 v = in[tid];
    vfloat4 o;
    o.x = fast_sigmoid(v.x);
    o.y = fast_sigmoid(v.y);
    o.z = fast_sigmoid(v.z);
    o.w = fast_sigmoid(v.w);
    __builtin_nontemporal_store(o, &out[tid]);
}

// ---------------------------------------------------------------------------
// Kernel 2: one thread per cell. Recomputes the 4 box channels from the raw
// input (overwrites the bulk kernel's sigmoid at those positions), then the
// per-cell max-IoU vs the image's 32 GT boxes -> noobj; zeroes obj.
// blockIdx.y = image b, blockIdx.x covers the 17328 cells of that image.
// ---------------------------------------------------------------------------
__global__ void noobj_fixup_kernel(const float* __restrict__ in, const float* __restrict__ gt,
                                   float* __restrict__ out,
                                   float* __restrict__ noobj, float* __restrict__ obj) {
    __shared__ float4 sbox[MM];
    int b = blockIdx.y;
    int t = threadIdx.x;
    if (t < MM) {
        const float* g = gt + (size_t)(b * MM + t) * 6;
        float cx = g[1], cy = g[2], gw = g[3], gh = g[4];
        sbox[t] = make_float4((cx - gw * 0.5f) * 608.0f, (cy - gh * 0.5f) * 608.0f,
                              (cx + gw * 0.5f) * 608.0f, (cy + gh * 0.5f) * 608.0f);
    }
    __syncthreads();
    int n = blockIdx.x * blockDim.x + t;
    if (n >= CELLS_PER_IMG) return;
    size_t cell = (size_t)b * CELLS_PER_IMG + n;

    // decode the 4 box channels of this cell from raw input
    const float* ip = in + cell * 85;
    int h = n % WW;
    int w = (n / WW) % WW;
    int a = n / (WW * WW);           // n < 3*76*76 so no %AA needed
    float px = fast_sigmoid(ip[0]) + (float)h;
    float py = fast_sigmoid(ip[1]) + (float)w;
    float pw = __builtin_amdgcn_exp2f(ip[2] * LOG2E) * (c_anchor[a][0] * 0.125f);
    float ph = __builtin_amdgcn_exp2f(ip[3] * LOG2E) * (c_anchor[a][1] * 0.125f);
    float* op = out + cell * 85;
    op[0] = px; op[1] = py; op[2] = pw; op[3] = ph;

    // replicate reference FP order: (val)/W * INPUTW
    float x1 = (px - pw * 0.5f) / 76.0f * 608.0f;
    float y1 = (py - ph * 0.5f) / 76.0f * 608.0f;
    float x2 = (px + pw * 0.5f) / 76.0f * 608.0f;
    float y2 = (py + ph * 0.5f) / 76.0f * 608.0f;
    float area2 = (x2 - x1) * (y2 - y1);
    float best = 0.0f;  // iou >= 0 always
#pragma unroll
    for (int m = 0; m < MM; ++m) {
        float4 gb = sbox[m];
        float area1 = (gb.z - gb.x) * (gb.w - gb.y);
        float ltx = fmaxf(gb.x, x1), lty = fmaxf(gb.y, y1);
        float rbx = fminf(gb.z, x2), rby = fminf(gb.w, y2);
        float inter = fmaxf(rbx - ltx, 0.0f) * fmaxf(rby - lty, 0.0f);
        float iou = inter * __builtin_amdgcn_rcpf(area1 + area2 - inter);
        best = fmaxf(best, iou);
    }
    noobj[cell] = (best <= 0.5f) ? 1.0f : 0.0f;
    obj[cell] = 0.0f;
}

// ---------------------------------------------------------------------------
// Kernel 3: per-GT best-anchor argmax (first-max tiebreak, exact fdiv kept to
// preserve argmax ordering). Idempotent constant scatter -> no atomics.
// ---------------------------------------------------------------------------
__global__ void assign_kernel(const float* __restrict__ gt,
                              float* __restrict__ noobj, float* __restrict__ obj) {
    int r = blockIdx.x * blockDim.x + threadIdx.x;
    if (r >= BB * MM) return;
    const float* g = gt + (size_t)r * 6;
    float cx = g[1], cy = g[2], gw = g[3], gh = g[4];
    float gx1 = (cx - gw * 0.5f) * 608.0f, gy1 = (cy - gh * 0.5f) * 608.0f;
    float gx2 = (cx + gw * 0.5f) * 608.0f, gy2 = (cy + gh * 0.5f) * 608.0f;
    float area_g = (gx2 - gx1) * (gy2 - gy1);
    int best = 0;
    float bestv = -1.0f;
#pragma unroll
    for (int k = 0; k < 9; ++k) {
        float ow = c_anchor[k][0] / 608.0f, oh = c_anchor[k][1] / 608.0f;
        float ax1 = (cx - ow * 0.5f) * 608.0f, ay1 = (cy - oh * 0.5f) * 608.0f;
        float ax2 = (cx + ow * 0.5f) * 608.0f, ay2 = (cy + oh * 0.5f) * 608.0f;
        float ltx = fmaxf(gx1, ax1), lty = fmaxf(gy1, ay1);
        float rbx = fminf(gx2, ax2), rby = fminf(gy2, ay2);
        float inter = fmaxf(rbx - ltx, 0.0f) * fmaxf(rby - lty, 0.0f);
        float area_a = (ax2 - ax1) * (ay2 - ay1);
        float v = inter / (area_g + area_a - inter);
        if (v > bestv) { bestv = v; best = k; }
    }
    if (best < AA) {
        int b = r / MM;  // reference uses row position, not the gt batch column
        int gi = (int)(cx * 76.0f);
        int gj = (int)(cy * 76.0f);
        int flat = ((b * AA + best) * WW + gi) * WW + gj;
        obj[flat] = 1.0f;
        noobj[flat] = 0.0f;
    }
}

extern "C" void kernel_launch(void* const* d_in, const int* in_sizes, int n_in,
                              void* d_out, int out_size, void* d_ws, size_t ws_size,
                              hipStream_t stream) {
    const float* pred = (const float*)d_in[0];
    const float* gt   = (const float*)d_in[1];
    float* dec   = (float*)d_out;            // 23,566,080
    float* noobj = dec + NDECODE;            //    277,248
    float* obj   = noobj + NCELLS;           //    277,248

    const int n4 = NDECODE / 4;              // 5,891,520
    bulk_sigmoid_kernel<<<(n4 + 255) / 256, 256, 0, stream>>>(
        (const vfloat4*)pred, (vfloat4*)dec);

    dim3 gb((CELLS_PER_IMG + 255) / 256, BB);
    noobj_fixup_kernel<<<gb, 256, 0, stream>>>(pred, gt, dec, noobj, obj);

    assign_kernel<<<2, 256, 0, stream>>>(gt, noobj, obj);
}

// Round 5
// 206.745 us; speedup vs baseline: 1.0662x; 1.0662x over previous
//
#include <hip/hip_runtime.h>
#include <math.h>

// ---- static config (mirrors reference) ----
#define BB 16
#define AA 3
#define NCC 80
#define WW 76
#define MM 32
#define CELLS_PER_IMG (AA * WW * WW)          // 17328
#define NDECODE (BB * CELLS_PER_IMG * 85)     // 23,566,080
#define NCELLS (BB * CELLS_PER_IMG)           // 277,248

typedef float vfloat4 __attribute__((ext_vector_type(4)));

__constant__ float c_anchor[9][2] = {
    {10.f,13.f},{16.f,30.f},{33.f,23.f},{30.f,61.f},{62.f,45.f},
    {59.f,119.f},{116.f,90.f},{156.f,198.f},{373.f,326.f}};

#define LOG2E 1.4426950408889634f

__device__ __forceinline__ float fast_sigmoid(float x) {
    return __builtin_amdgcn_rcpf(1.0f + __builtin_amdgcn_exp2f(-x * LOG2E));
}

// ---------------------------------------------------------------------------
// Kernel 1: branchless streaming sigmoid over the whole tensor. The 4 box
// channels per cell (4/85 of elements) get a WRONG value here; kernel 2
// overwrites them. Plain stores (L2 write-back): nontemporal bypass measured
// SLOWER end-to-end (R4: fill BW dropped 6.1->5.3 TB/s, total +19 us).
// ---------------------------------------------------------------------------
__global__ void bulk_sigmoid_kernel(const vfloat4* __restrict__ in, vfloat4* __restrict__ out) {
    const int n4 = NDECODE / 4;
    int tid = blockIdx.x * blockDim.x + threadIdx.x;
    if (tid >= n4) return;
    vfloat4 v = in[tid];
    vfloat4 o;
    o.x = fast_sigmoid(v.x);
    o.y = fast_sigmoid(v.y);
    o.z = fast_sigmoid(v.z);
    o.w = fast_sigmoid(v.w);
    out[tid] = o;
}

// ---------------------------------------------------------------------------
// Kernel 2: one thread per cell. Recomputes the 4 box channels from the raw
// input (overwrites the bulk kernel's sigmoid at those positions), then the
// per-cell max-IoU vs the image's 32 GT boxes -> noobj; zeroes obj.
// blockIdx.y = image b, blockIdx.x covers the 17328 cells of that image.
// ---------------------------------------------------------------------------
__global__ void noobj_fixup_kernel(const float* __restrict__ in, const float* __restrict__ gt,
                                   float* __restrict__ out,
                                   float* __restrict__ noobj, float* __restrict__ obj) {
    __shared__ float4 sbox[MM];
    int b = blockIdx.y;
    int t = threadIdx.x;
    if (t < MM) {
        const float* g = gt + (size_t)(b * MM + t) * 6;
        float cx = g[1], cy = g[2], gw = g[3], gh = g[4];
        sbox[t] = make_float4((cx - gw * 0.5f) * 608.0f, (cy - gh * 0.5f) * 608.0f,
                              (cx + gw * 0.5f) * 608.0f, (cy + gh * 0.5f) * 608.0f);
    }
    __syncthreads();
    int n = blockIdx.x * blockDim.x + t;
    if (n >= CELLS_PER_IMG) return;
    size_t cell = (size_t)b * CELLS_PER_IMG + n;

    // decode the 4 box channels of this cell from raw input
    const float* ip = in + cell * 85;
    int h = n % WW;
    int w = (n / WW) % WW;
    int a = n / (WW * WW);           // n < 3*76*76 so no %AA needed
    float px = fast_sigmoid(ip[0]) + (float)h;
    float py = fast_sigmoid(ip[1]) + (float)w;
    float pw = __builtin_amdgcn_exp2f(ip[2] * LOG2E) * (c_anchor[a][0] * 0.125f);
    float ph = __builtin_amdgcn_exp2f(ip[3] * LOG2E) * (c_anchor[a][1] * 0.125f);
    float* op = out + cell * 85;
    op[0] = px; op[1] = py; op[2] = pw; op[3] = ph;

    // replicate reference FP order: (val)/W * INPUTW
    float x1 = (px - pw * 0.5f) / 76.0f * 608.0f;
    float y1 = (py - ph * 0.5f) / 76.0f * 608.0f;
    float x2 = (px + pw * 0.5f) / 76.0f * 608.0f;
    float y2 = (py + ph * 0.5f) / 76.0f * 608.0f;
    float area2 = (x2 - x1) * (y2 - y1);
    float best = 0.0f;  // iou >= 0 always
#pragma unroll
    for (int m = 0; m < MM; ++m) {
        float4 gb = sbox[m];
        float area1 = (gb.z - gb.x) * (gb.w - gb.y);
        float ltx = fmaxf(gb.x, x1), lty = fmaxf(gb.y, y1);
        float rbx = fminf(gb.z, x2), rby = fminf(gb.w, y2);
        float inter = fmaxf(rbx - ltx, 0.0f) * fmaxf(rby - lty, 0.0f);
        float iou = inter * __builtin_amdgcn_rcpf(area1 + area2 - inter);
        best = fmaxf(best, iou);
    }
    noobj[cell] = (best <= 0.5f) ? 1.0f : 0.0f;
    obj[cell] = 0.0f;
}

// ---------------------------------------------------------------------------
// Kernel 3: per-GT best-anchor argmax (first-max tiebreak, exact fdiv kept to
// preserve argmax ordering). Idempotent constant scatter -> no atomics.
// ---------------------------------------------------------------------------
__global__ void assign_kernel(const float* __restrict__ gt,
                              float* __restrict__ noobj, float* __restrict__ obj) {
    int r = blockIdx.x * blockDim.x + threadIdx.x;
    if (r >= BB * MM) return;
    const float* g = gt + (size_t)r * 6;
    float cx = g[1], cy = g[2], gw = g[3], gh = g[4];
    float gx1 = (cx - gw * 0.5f) * 608.0f, gy1 = (cy - gh * 0.5f) * 608.0f;
    float gx2 = (cx + gw * 0.5f) * 608.0f, gy2 = (cy + gh * 0.5f) * 608.0f;
    float area_g = (gx2 - gx1) * (gy2 - gy1);
    int best = 0;
    float bestv = -1.0f;
#pragma unroll
    for (int k = 0; k < 9; ++k) {
        float ow = c_anchor[k][0] / 608.0f, oh = c_anchor[k][1] / 608.0f;
        float ax1 = (cx - ow * 0.5f) * 608.0f, ay1 = (cy - oh * 0.5f) * 608.0f;
        float ax2 = (cx + ow * 0.5f) * 608.0f, ay2 = (cy + oh * 0.5f) * 608.0f;
        float ltx = fmaxf(gx1, ax1), lty = fmaxf(gy1, ay1);
        float rbx = fminf(gx2, ax2), rby = fminf(gy2, ay2);
        float inter = fmaxf(rbx - ltx, 0.0f) * fmaxf(rby - lty, 0.0f);
        float area_a = (ax2 - ax1) * (ay2 - ay1);
        float v = inter / (area_g + area_a - inter);
        if (v > bestv) { bestv = v; best = k; }
    }
    if (best < AA) {
        int b = r / MM;  // reference uses row position, not the gt batch column
        int gi = (int)(cx * 76.0f);
        int gj = (int)(cy * 76.0f);
        int flat = ((b * AA + best) * WW + gi) * WW + gj;
        obj[flat] = 1.0f;
        noobj[flat] = 0.0f;
    }
}

extern "C" void kernel_launch(void* const* d_in, const int* in_sizes, int n_in,
                              void* d_out, int out_size, void* d_ws, size_t ws_size,
                              hipStream_t stream) {
    const float* pred = (const float*)d_in[0];
    const float* gt   = (const float*)d_in[1];
    float* dec   = (float*)d_out;            // 23,566,080
    float* noobj = dec + NDECODE;            //    277,248
    float* obj   = noobj + NCELLS;           //    277,248

    const int n4 = NDECODE / 4;              // 5,891,520
    bulk_sigmoid_kernel<<<(n4 + 255) / 256, 256, 0, stream>>>(
        (const vfloat4*)pred, (vfloat4*)dec);

    dim3 gb((CELLS_PER_IMG + 255) / 256, BB);
    noobj_fixup_kernel<<<gb, 256, 0, stream>>>(pred, gt, dec, noobj, obj);

    assign_kernel<<<2, 256, 0, stream>>>(gt, noobj, obj);
}